// Round 16
// baseline (69.084 us; speedup 1.0000x reference)
//
#include <hip/hip_runtime.h>

// ---------------------------------------------------------------------------
// LMU fused cell on MI355X (gfx950).  Round 16: prep-free fused GEMM.
//   new_h = sigmoid([x|h|m] @ [Wx|Wh|Wm@AT]^T + u*(Wm@BT)^T)
//   new_m = m @ AT^T + u*BT^T     u = [x|h|m].e  (via epack MFMA, bf16)
// K0 lmu_wpack: weights only -> wpack/atpack/wu/epack (+Wm2).  ~1.1 MB ws.
// K1 lmu_gemm: R13/R14 drain-barrier schedule, BK=32 x 28 chunks, BM=128
//   BN=128, 512 thr, dbuf 2x32KB.  A staged as RAW F32 from x|h|m via
//   global_load_lds (no prep pass); f32->bf16 conversion in-register at the
//   LDS->MFMA boundary.  u via 2 extra MFMAs/chunk vs epack col0 (wc==0).
//   new_m side-GEMM on chunks 20-27 (B = atpack, LDS-staged).
// ---------------------------------------------------------------------------

typedef __bf16 bf16;
typedef bf16  bf16x8 __attribute__((ext_vector_type(8)));
typedef float f32x4  __attribute__((ext_vector_type(4)));
typedef unsigned short u16;

#define BATCH 16384
// ws offsets (u16 units)
#define WPACK 0            // [896/8][512][8] = 458752  (kk>=80 = Wm@AT)
#define ATPACK 458752      // [256/8][256][8] = 65536
#define WUOFF 524288       // 512 f32  (1024 u16)
#define EPACK 525312       // [112][16][8] = 14336 (col0 = e, rest 0)
// end: 539648 u16 = ~1.08 MB

#define PACK_ITEMS 408064  // 327680 + 65536 + 512 + 14336 = 797*512
#define PACKA_BLOCKS 797
#define WM2_BLOCKS 128

__device__ __forceinline__ u16 f2bf(float f) {
  unsigned u = __builtin_bit_cast(unsigned, f);
  u += 0x7FFFu + ((u >> 16) & 1u);   // RNE
  return (u16)(u >> 16);
}

__device__ __forceinline__ void gload16(const void* g, void* l) {
  __builtin_amdgcn_global_load_lds(
      (const __attribute__((address_space(1))) unsigned int*)g,
      (__attribute__((address_space(3))) unsigned int*)l, 16, 0, 0);
}

// ---------------- K0: weight prologue (wpack + wm2) -------------------------
__global__ __launch_bounds__(512) void lmu_wpack(
    const float* __restrict__ Wx, const float* __restrict__ Wh,
    const float* __restrict__ Wm, const float* __restrict__ AT,
    const float* __restrict__ BT, const float* __restrict__ ex,
    const float* __restrict__ eh, const float* __restrict__ em,
    u16* __restrict__ ws) {
  __shared__ float wmt[16 * 256];
  const int bx = blockIdx.x;
  const int t  = threadIdx.x;
  if (bx < PACKA_BLOCKS) {
    int i = bx * 512 + t;
    if (i < 327680) {                     // Wall^T[k][n], k<640
      int j = i & 7, rest = i >> 3;
      int n = rest & 511, kk = rest >> 9;
      int k = kk * 8 + j;
      float v = (k < 128) ? Wx[n * 128 + k] : Wh[n * 512 + (k - 128)];
      ws[WPACK + i] = f2bf(v);
    } else if (i < 393216) {              // atpack[kk][d][j] = AT[d][kk*8+j]
      int tt = i - 327680;
      int j = tt & 7, rest = tt >> 3;
      int d = rest & 255, kk = rest >> 8;
      ws[ATPACK + tt] = f2bf(AT[d * 256 + kk * 8 + j]);
    } else if (i < 393728) {              // wu[n] = dot(Wm[n,:], BT)
      int n = i - 393216;
      float s = 0.f;
      for (int k = 0; k < 256; k += 4) {
        float4 wv = *(const float4*)(Wm + (size_t)n * 256 + k);
        float4 bv = *(const float4*)(BT + k);
        s += wv.x * bv.x + wv.y * bv.y + wv.z * bv.z + wv.w * bv.w;
      }
      ((float*)(ws + WUOFF))[n] = s;
    } else {                              // epack[kk][col][j]: col0 = e
      int tt = i - 393728;
      int j = tt & 7, rest = tt >> 3;
      int col = rest & 15, kk = rest >> 4;
      int k = kk * 8 + j;
      float v = 0.f;
      if (col == 0)
        v = (k < 128) ? ex[k] : (k < 640) ? eh[k - 128] : em[k - 640];
      ws[EPACK + tt] = f2bf(v);
    }
  } else {                                // Wm2 = Wm @ AT (16r x 64d tiles)
    const int wq = bx - PACKA_BLOCKS;
    const int nb = (wq & 31) * 16, db = (wq >> 5) * 64;
#pragma unroll
    for (int it = 0; it < 2; ++it) {
      int f = it * 512 + t;
      float4 v = *(const float4*)(Wm + (size_t)(nb + (f >> 6)) * 256 + (f & 63) * 4);
      *(float4*)(wmt + (f >> 6) * 256 + (f & 63) * 4) = v;
    }
    __syncthreads();
    const int d = db + (t & 63);
    const int nn = (t >> 6) * 2;
    float acc[2] = {0.f, 0.f};
    for (int k = 0; k < 256; ++k) {
      float atv = AT[(size_t)k * 256 + d];
#pragma unroll
      for (int i2 = 0; i2 < 2; ++i2) acc[i2] += wmt[(nn + i2) * 256 + k] * atv;
    }
    const int kk = 80 + (d >> 3), j = d & 7;
#pragma unroll
    for (int i2 = 0; i2 < 2; ++i2)
      ws[WPACK + ((size_t)kk * 512 + (nb + nn + i2)) * 8 + j] = f2bf(acc[i2]);
  }
}

// ---------------- K1: fused GEMM (A = raw f32, cvt at LDS->MFMA) ------------
// grid 512 = 128 M-tiles x 4 N-slices; 512 thr; LDS 64KB (2 x 32KB dbuf).
// per 32KB buffer (u16 units): A-f32 [8kb][128r][4f32] @0 (8192),
//   B [4kk][128n][8] @8192 (4096), S [4kk][128dup][8] @12288 (4096).
__global__ __launch_bounds__(512, 2) void lmu_gemm(
    const float* __restrict__ x, const float* __restrict__ h,
    const float* __restrict__ m, const float* __restrict__ BT,
    const u16* __restrict__ ws, float* __restrict__ out) {
  __shared__ __align__(16) u16 smem[2 * 16384];
  const int tid  = threadIdx.x;
  const int lane = tid & 63;
  const int w    = tid >> 6;     // 0..7
  const int wr   = w >> 1;       // 0..3 (32-row slice)
  const int wc   = w & 1;        // 0..1 (64-col slice)
  const int lm   = lane & 15;
  const int kg   = lane >> 4;    // 0..3
  const int bid  = blockIdx.x;
  const int mi   = (bid & 7) | ((bid >> 5) << 3);  // same-M N-slices -> same XCD
  const int nsl  = (bid >> 3) & 3;
  const int b0   = mi * 128;

  const u16* wpk = ws + WPACK;
  const u16* atp = ws + ATPACK;
  const u16* epk = ws + EPACK;

  f32x4 acc[2][4];    // new_h: 2 Mfrag x 4 Nfrag (32r x 64c per wave)
  f32x4 acc2[2][2];   // new_m: 2 Mfrag x 2 Nfrag (32c per wave)
  f32x4 accu[2];      // u column (wc==0 waves)
#pragma unroll
  for (int mt = 0; mt < 2; ++mt) {
#pragma unroll
    for (int ct = 0; ct < 4; ++ct) acc[mt][ct] = (f32x4){0.f, 0.f, 0.f, 0.f};
#pragma unroll
    for (int ct = 0; ct < 2; ++ct) acc2[mt][ct] = (f32x4){0.f, 0.f, 0.f, 0.f};
    accu[mt] = (f32x4){0.f, 0.f, 0.f, 0.f};
  }

  auto stage = [&](int c) {
    u16* buf = smem + (c & 1) * 16384;
    // A: 128 rows x 32 k f32 = 16KB -> [kb][r][4f32], 2 loads/thread
    const float* base;
    int stride, koff;
    if (c < 4)       { base = x; stride = 128; koff = c * 32; }
    else if (c < 20) { base = h; stride = 512; koff = (c - 4) * 32; }
    else             { base = m; stride = 256; koff = (c - 20) * 32; }
#pragma unroll
    for (int ph = 0; ph < 2; ++ph) {
      int i = ph * 512 + tid;
      int kb = i >> 7, r = i & 127;
      gload16(base + (size_t)(b0 + r) * stride + koff + kb * 4, buf + i * 8);
    }
    // B: 4kk x 128n x 8 = 8KB -> 1 load/thread
    gload16(wpk + ((size_t)(c * 4 + (tid >> 7)) * 512 + nsl * 128 + (tid & 127)) * 8,
            buf + 8192 + tid * 8);
    if (c >= 20) {   // S: 4kk x 64n dup-> 128 = 8KB -> 1 load/thread
      int cm = c - 20;
      gload16(atp + ((size_t)(cm * 4 + (tid >> 7)) * 256 + nsl * 64 + (tid & 63)) * 8,
              buf + 12288 + tid * 8);
    }
  };

  auto mma = [&](int c) {
    const u16* buf = smem + (c & 1) * 16384;
    // A frags: read f32 from LDS, convert to bf16 in-register
    bf16x8 a[2];
#pragma unroll
    for (int mt = 0; mt < 2; ++mt) {
      int row = wr * 32 + mt * 16 + lm;
      f32x4 lo = *(const f32x4*)(buf + ((kg * 2 + 0) * 128 + row) * 8);
      f32x4 hi = *(const f32x4*)(buf + ((kg * 2 + 1) * 128 + row) * 8);
      a[mt] = (bf16x8){(bf16)lo[0], (bf16)lo[1], (bf16)lo[2], (bf16)lo[3],
                       (bf16)hi[0], (bf16)hi[1], (bf16)hi[2], (bf16)hi[3]};
    }
#pragma unroll
    for (int ct = 0; ct < 4; ++ct) {
      bf16x8 b = *(const bf16x8*)(buf + 8192 + (kg * 128 + wc * 64 + ct * 16 + lm) * 8);
#pragma unroll
      for (int mt = 0; mt < 2; ++mt)
        acc[mt][ct] = __builtin_amdgcn_mfma_f32_16x16x32_bf16(a[mt], b, acc[mt][ct], 0, 0, 0);
    }
    if (c >= 20) {
#pragma unroll
      for (int ct = 0; ct < 2; ++ct) {
        bf16x8 s = *(const bf16x8*)(buf + 12288 + (kg * 128 + wc * 32 + ct * 16 + lm) * 8);
#pragma unroll
        for (int mt = 0; mt < 2; ++mt)
          acc2[mt][ct] = __builtin_amdgcn_mfma_f32_16x16x32_bf16(a[mt], s, acc2[mt][ct], 0, 0, 0);
      }
    }
    if (wc == 0) {   // u-column MFMA vs epack col0 (L2-hot 28KB)
      bf16x8 be = *(const bf16x8*)(epk + ((size_t)(c * 4 + kg) * 16 + lm) * 8);
#pragma unroll
      for (int mt = 0; mt < 2; ++mt)
        accu[mt] = __builtin_amdgcn_mfma_f32_16x16x32_bf16(a[mt], be, accu[mt], 0, 0, 0);
    }
  };

  stage(0);
  __syncthreads();
#pragma unroll 2
  for (int c = 0; c < 28; ++c) {
    if (c < 27) stage(c + 1);   // issue next-chunk loads first (overlap)
    mma(c);                     // compute current from LDS
    __syncthreads();            // drain (R13-proven schedule)
  }

  // ---- u exchange through dead LDS ----
  float* uL = (float*)smem;
  if (wc == 0 && lm == 0) {
#pragma unroll
    for (int mt = 0; mt < 2; ++mt)
#pragma unroll
      for (int j = 0; j < 4; ++j)
        uL[wr * 32 + mt * 16 + kg * 4 + j] = accu[mt][j];
  }
  __syncthreads();

  // ---- epilogue ----
  const float* wuf = (const float*)(ws + WUOFF);
  float wuv[4], btv[2];
#pragma unroll
  for (int ct = 0; ct < 4; ++ct) wuv[ct] = wuf[nsl * 128 + wc * 64 + ct * 16 + lm];
#pragma unroll
  for (int ct = 0; ct < 2; ++ct) btv[ct] = BT[nsl * 64 + wc * 32 + ct * 16 + lm];
  float* outm = out + (size_t)BATCH * 512;
#pragma unroll
  for (int mt = 0; mt < 2; ++mt)
#pragma unroll
    for (int j = 0; j < 4; ++j) {
      int rl = wr * 32 + mt * 16 + kg * 4 + j;
      size_t row = (size_t)(b0 + rl);
      float uv = uL[rl];
#pragma unroll
      for (int ct = 0; ct < 4; ++ct) {
        float v = acc[mt][ct][j] + uv * wuv[ct];
        out[row * 512 + nsl * 128 + wc * 64 + ct * 16 + lm] = 1.0f / (1.0f + __expf(-v));
      }
#pragma unroll
      for (int ct = 0; ct < 2; ++ct)
        outm[row * 256 + nsl * 64 + wc * 32 + ct * 16 + lm] = acc2[mt][ct][j] + uv * btv[ct];
    }
}

extern "C" void kernel_launch(void* const* d_in, const int* in_sizes, int n_in,
                              void* d_out, int out_size, void* d_ws, size_t ws_size,
                              hipStream_t stream) {
  const float* x  = (const float*)d_in[0];
  const float* h  = (const float*)d_in[1];
  const float* m  = (const float*)d_in[2];
  const float* Wx = (const float*)d_in[3];
  const float* Wh = (const float*)d_in[4];
  const float* Wm = (const float*)d_in[5];
  const float* ex = (const float*)d_in[6];
  const float* eh = (const float*)d_in[7];
  const float* em = (const float*)d_in[8];
  const float* AT = (const float*)d_in[9];
  const float* BT = (const float*)d_in[10];
  float* out = (float*)d_out;
  u16* ws = (u16*)d_ws;   // uses ~1.08 MB

  lmu_wpack<<<PACKA_BLOCKS + WM2_BLOCKS, 512, 0, stream>>>(
      Wx, Wh, Wm, AT, BT, ex, eh, em, ws);
  lmu_gemm<<<512, 512, 0, stream>>>(x, h, m, BT, ws, out);
}

// Round 17
// 53.821 us; speedup vs baseline: 1.2836x; 1.2836x over previous
//
#include <hip/hip_runtime.h>

// ---------------------------------------------------------------------------
// LMU fused cell on MI355X (gfx950).  Round 17: R14 base + m-first chunk
// order (new_m write overlapped with compute) + u prefetch.
//   new_h = sigmoid([x|h|m] @ [Wx|Wh|Wm@AT]^T + u*(Wm@BT)^T)
//   new_m = m @ AT^T + u*BT^T     u = [x|h|m].e  (f32 exact, in prep)
// K0 lmu_pre: merged weight-pack + Wm2 + wu + A-pack/u prep (one dispatch).
// K1 lmu_gemm: R13/R14 drain schedule (512 blk x 512 thr, BM=128 BN=128,
//   BK=64 x 14, dbuf 80KB, 2 blk/CU).  Chunks 0-3 = m segment (+side-S
//   GEMM); new_m stored at iteration 4 (overlaps 10 chunks of compute);
//   chunks 4-5 = x, 6-13 = h.  u prefetched to regs before the K-loop.
// ---------------------------------------------------------------------------

typedef __bf16 bf16;
typedef bf16  bf16x8 __attribute__((ext_vector_type(8)));
typedef float f32x4  __attribute__((ext_vector_type(4)));
typedef unsigned short u16;

#define BATCH 16384
// ws offsets (u16 units)
#define WPACK 0            // [896/8][512][8] = 458752  (kk>=80 = Wm@AT)
#define ATPACK 458752      // [256/8][256][8] = 65536
#define WUOFF 524288       // 512 f32  (1024 u16)
#define UOFF  525312       // 16384 f32 (32768 u16)
#define APACK 558080       // 16384*896 u16 (row-major, k = [x|h|m])
// end: 15,238,144 u16 = ~30.5 MB

#define PACK_ITEMS 393728  // 327680 + 65536 + 512
#define PACK_BLOCKS 1538
#define WM2_BLOCKS 128
#define PREP_BLOCKS 4096   // 4 rows/block

__device__ __forceinline__ u16 f2bf(float f) {
  unsigned u = __builtin_bit_cast(unsigned, f);
  u += 0x7FFFu + ((u >> 16) & 1u);   // RNE
  return (u16)(u >> 16);
}

__device__ __forceinline__ void gload16(const u16* g, u16* l) {
  __builtin_amdgcn_global_load_lds(
      (const __attribute__((address_space(1))) unsigned int*)g,
      (__attribute__((address_space(3))) unsigned int*)l, 16, 0, 0);
}

// ---------------- K0: merged prologue (wpack + wm2 + prep), R14-verbatim ----
__global__ __launch_bounds__(256) void lmu_pre(
    const float* __restrict__ Wx, const float* __restrict__ Wh,
    const float* __restrict__ Wm, const float* __restrict__ AT,
    const float* __restrict__ BT, const float* __restrict__ x,
    const float* __restrict__ h, const float* __restrict__ m,
    const float* __restrict__ ex, const float* __restrict__ eh,
    const float* __restrict__ em, u16* __restrict__ ws) {
  __shared__ float wmt[16 * 256];
  const int bx = blockIdx.x;
  if (bx < PACK_BLOCKS) {
    int i = bx * 256 + threadIdx.x;
    if (i < 327680) {                     // Wall^T[k][n], k<640
      int j = i & 7, rest = i >> 3;
      int n = rest & 511, kk = rest >> 9;
      int k = kk * 8 + j;
      float v = (k < 128) ? Wx[n * 128 + k] : Wh[n * 512 + (k - 128)];
      ws[WPACK + i] = f2bf(v);
    } else if (i < 393216) {              // atpack[kk][d][j] = AT[d][kk*8+j]
      int t = i - 327680;
      int j = t & 7, rest = t >> 3;
      int d = rest & 255, kk = rest >> 8;
      ws[ATPACK + t] = f2bf(AT[d * 256 + kk * 8 + j]);
    } else if (i < PACK_ITEMS) {          // wu[n] = dot(Wm[n,:], BT)
      int n = i - 393216;
      float s = 0.f;
      for (int k = 0; k < 256; k += 4) {
        float4 wv = *(const float4*)(Wm + (size_t)n * 256 + k);
        float4 bv = *(const float4*)(BT + k);
        s += wv.x * bv.x + wv.y * bv.y + wv.z * bv.z + wv.w * bv.w;
      }
      ((float*)(ws + WUOFF))[n] = s;
    }
  } else if (bx < PACK_BLOCKS + WM2_BLOCKS) {   // Wm2 = Wm @ AT
    const int wq = bx - PACK_BLOCKS;
    const int t = threadIdx.x;
    const int nb = (wq & 31) * 16, db = (wq >> 5) * 64;
#pragma unroll
    for (int it = 0; it < 4; ++it) {
      int f = it * 256 + t;
      float4 v = *(const float4*)(Wm + (size_t)(nb + (f >> 6)) * 256 + (f & 63) * 4);
      *(float4*)(wmt + (f >> 6) * 256 + (f & 63) * 4) = v;
    }
    __syncthreads();
    const int d = db + (t & 63);
    const int nn = (t >> 6) * 4;
    float acc[4] = {0.f, 0.f, 0.f, 0.f};
    for (int k = 0; k < 256; ++k) {
      float atv = AT[(size_t)k * 256 + d];
#pragma unroll
      for (int i2 = 0; i2 < 4; ++i2) acc[i2] += wmt[(nn + i2) * 256 + k] * atv;
    }
    const int kk = 80 + (d >> 3), j = d & 7;
#pragma unroll
    for (int i2 = 0; i2 < 4; ++i2)
      ws[WPACK + ((size_t)kk * 512 + (nb + nn + i2)) * 8 + j] = f2bf(acc[i2]);
  } else {                                      // A-pack + u (f32 exact)
    const int lane = threadIdx.x & 63;
    const int row  = (bx - PACK_BLOCKS - WM2_BLOCKS) * 4 + (threadIdx.x >> 6);
    u16* ap = ws + APACK + (size_t)row * 896;
    float s = 0.f;
#pragma unroll
    for (int j = 0; j < 4; ++j) {
      int slot = j * 64 + lane;
      if (slot < 224) {
        float4 a, e;
        if (slot < 32)       { int c = slot * 4;
          a = *(const float4*)(x + (size_t)row * 128 + c); e = *(const float4*)(ex + c); }
        else if (slot < 160) { int c = (slot - 32) * 4;
          a = *(const float4*)(h + (size_t)row * 512 + c); e = *(const float4*)(eh + c); }
        else                 { int c = (slot - 160) * 4;
          a = *(const float4*)(m + (size_t)row * 256 + c); e = *(const float4*)(em + c); }
        s += a.x * e.x + a.y * e.y + a.z * e.z + a.w * e.w;
        unsigned long long pk =
            (unsigned long long)f2bf(a.x)
          | ((unsigned long long)f2bf(a.y) << 16)
          | ((unsigned long long)f2bf(a.z) << 32)
          | ((unsigned long long)f2bf(a.w) << 48);
        *(unsigned long long*)(ap + slot * 4) = pk;
      }
    }
#pragma unroll
    for (int d = 1; d < 64; d <<= 1) s += __shfl_xor(s, d);
    if (lane == 0) ((float*)(ws + UOFF))[row] = s;
  }
}

// chunk c -> k-offset into the 896-wide concatenated [x|h|m] axis.
// m first (640..895), then x (0..127), then h (128..639).
__device__ __forceinline__ int koff_of(int c) {
  return (c < 4) ? (640 + c * 64) : (c < 6) ? ((c - 4) * 64) : (128 + (c - 6) * 64);
}

// ---------------- K1: main GEMM (R13 schedule, m-first order) ---------------
// grid 512 = 128 M-tiles x 4 N-slices; 512 thr; LDS 80KB (2 x 40KB dbuf).
// per 40KB buffer: A [8kb][128r][8] @0, B [8kk][128n][8] @8192 u16,
//                  S [8kk][64n][8] @16384 u16 (staged only for c<4).
__global__ __launch_bounds__(512, 4) void lmu_gemm(
    const u16* __restrict__ ws, const float* __restrict__ BT,
    float* __restrict__ out) {
  __shared__ __align__(16) u16 smem[2 * 20480];
  const int tid  = threadIdx.x;
  const int lane = tid & 63;
  const int w    = tid >> 6;     // 0..7
  const int wr   = w >> 1;       // 0..3 (32-row slice)
  const int wc   = w & 1;        // 0..1 (64-col slice)
  const int lm   = lane & 15;
  const int kg   = lane >> 4;
  const int bid  = blockIdx.x;
  const int mi   = (bid & 7) | ((bid >> 5) << 3);  // same-M N-slices -> same XCD
  const int nsl  = (bid >> 3) & 3;
  const int b0   = mi * 128;

  const u16* apack = ws + APACK;
  const u16* wpk   = ws + WPACK;
  const u16* atp   = ws + ATPACK;
  const float* uf  = (const float*)(ws + UOFF);
  const float* wuf = (const float*)(ws + WUOFF);
  float* outm = out + (size_t)BATCH * 512;

  // prefetch epilogue constants + u values (removes epilogue latency tail)
  float wuv[4], btv[2], ureg[2][4];
#pragma unroll
  for (int ct = 0; ct < 4; ++ct) wuv[ct] = wuf[nsl * 128 + wc * 64 + ct * 16 + lm];
#pragma unroll
  for (int ct = 0; ct < 2; ++ct) btv[ct] = BT[nsl * 64 + wc * 32 + ct * 16 + lm];
#pragma unroll
  for (int mt = 0; mt < 2; ++mt)
#pragma unroll
    for (int j = 0; j < 4; ++j)
      ureg[mt][j] = uf[b0 + wr * 32 + mt * 16 + kg * 4 + j];

  f32x4 acc[2][4];    // new_h: 2 Mfrag x 4 Nfrag (32r x 64c per wave)
  f32x4 acc2[2][2];   // new_m: 2 Mfrag x 2 Nfrag (32c per wave)
#pragma unroll
  for (int mt = 0; mt < 2; ++mt) {
#pragma unroll
    for (int ct = 0; ct < 4; ++ct) acc[mt][ct] = (f32x4){0.f, 0.f, 0.f, 0.f};
#pragma unroll
    for (int ct = 0; ct < 2; ++ct) acc2[mt][ct] = (f32x4){0.f, 0.f, 0.f, 0.f};
  }

  auto stage = [&](int c) {
    u16* buf = smem + (c & 1) * 20480;
    const int ko = koff_of(c);
#pragma unroll
    for (int ph = 0; ph < 2; ++ph) {           // A chunk: 16KB
      int i = ph * 512 + tid;
      int kb = i >> 7, r = i & 127;
      gload16(apack + (size_t)(b0 + r) * 896 + ko + kb * 8, buf + i * 8);
    }
#pragma unroll
    for (int ph = 0; ph < 2; ++ph) {           // B chunk: 16KB
      int i = ph * 512 + tid;
      int kk = i >> 7, n = i & 127;
      gload16(wpk + ((size_t)(ko / 8 + kk) * 512 + nsl * 128 + n) * 8,
              buf + 8192 + i * 8);
    }
    if (c < 4) {                                // side B (atpack): 8KB
      int kk = tid >> 6, n = tid & 63;
      gload16(atp + ((size_t)(c * 8 + kk) * 256 + nsl * 64 + n) * 8,
              buf + 16384 + tid * 8);
    }
  };

  auto mma = [&](int c) {
    const u16* buf = smem + (c & 1) * 20480;
#pragma unroll
    for (int ks = 0; ks < 2; ++ks) {
      const int kq = ks * 4 + kg;
      bf16x8 a[2];
#pragma unroll
      for (int mt = 0; mt < 2; ++mt)
        a[mt] = *(const bf16x8*)(buf + (kq * 128 + wr * 32 + mt * 16 + lm) * 8);
#pragma unroll
      for (int ct = 0; ct < 4; ++ct) {
        bf16x8 b = *(const bf16x8*)(buf + 8192 + (kq * 128 + wc * 64 + ct * 16 + lm) * 8);
#pragma unroll
        for (int mt = 0; mt < 2; ++mt)
          acc[mt][ct] = __builtin_amdgcn_mfma_f32_16x16x32_bf16(a[mt], b, acc[mt][ct], 0, 0, 0);
      }
      if (c < 4) {                              // new_m side-GEMM
#pragma unroll
        for (int ct = 0; ct < 2; ++ct) {
          bf16x8 b = *(const bf16x8*)(buf + 16384 + (kq * 64 + wc * 32 + ct * 16 + lm) * 8);
#pragma unroll
          for (int mt = 0; mt < 2; ++mt)
            acc2[mt][ct] = __builtin_amdgcn_mfma_f32_16x16x32_bf16(a[mt], b, acc2[mt][ct], 0, 0, 0);
        }
      }
    }
  };

  stage(0);
  __syncthreads();
#pragma unroll
  for (int c = 0; c < 14; ++c) {
    if (c == 4) {
      // acc2 complete (chunks 0-3); store new_m now -> write overlaps
      // the remaining 10 chunks of staging+MFMA.
#pragma unroll
      for (int mt = 0; mt < 2; ++mt)
#pragma unroll
        for (int j = 0; j < 4; ++j) {
          int rl = wr * 32 + mt * 16 + kg * 4 + j;
          size_t row = (size_t)(b0 + rl);
#pragma unroll
          for (int ct = 0; ct < 2; ++ct)
            outm[row * 256 + nsl * 64 + wc * 32 + ct * 16 + lm] =
                acc2[mt][ct][j] + ureg[mt][j] * btv[ct];
        }
    }
    if (c < 13) stage(c + 1);   // issue next-chunk loads first (overlap)
    mma(c);                     // compute current from LDS
    __syncthreads();            // drain (measured-best schedule)
  }

  // ---- epilogue: new_h only (pure stores, constants preloaded) ----
#pragma unroll
  for (int mt = 0; mt < 2; ++mt)
#pragma unroll
    for (int j = 0; j < 4; ++j) {
      int rl = wr * 32 + mt * 16 + kg * 4 + j;
      size_t row = (size_t)(b0 + rl);
      float uv = ureg[mt][j];
#pragma unroll
      for (int ct = 0; ct < 4; ++ct) {
        float v = acc[mt][ct][j] + uv * wuv[ct];
        out[row * 512 + nsl * 128 + wc * 64 + ct * 16 + lm] = 1.0f / (1.0f + __expf(-v));
      }
    }
}

extern "C" void kernel_launch(void* const* d_in, const int* in_sizes, int n_in,
                              void* d_out, int out_size, void* d_ws, size_t ws_size,
                              hipStream_t stream) {
  const float* x  = (const float*)d_in[0];
  const float* h  = (const float*)d_in[1];
  const float* m  = (const float*)d_in[2];
  const float* Wx = (const float*)d_in[3];
  const float* Wh = (const float*)d_in[4];
  const float* Wm = (const float*)d_in[5];
  const float* ex = (const float*)d_in[6];
  const float* eh = (const float*)d_in[7];
  const float* em = (const float*)d_in[8];
  const float* AT = (const float*)d_in[9];
  const float* BT = (const float*)d_in[10];
  float* out = (float*)d_out;
  u16* ws = (u16*)d_ws;   // uses ~30.5 MB

  lmu_pre<<<PACK_BLOCKS + WM2_BLOCKS + PREP_BLOCKS, 256, 0, stream>>>(
      Wx, Wh, Wm, AT, BT, x, h, m, ex, eh, em, ws);
  lmu_gemm<<<512, 512, 0, stream>>>(ws, BT, out);
}

// Round 18
// 51.484 us; speedup vs baseline: 1.3419x; 1.0454x over previous
//
#include <hip/hip_runtime.h>

// ---------------------------------------------------------------------------
// LMU fused cell on MI355X (gfx950).  Round 18: tile-major A-pack.
//   new_h = sigmoid([x|h|m] @ [Wx|Wh|Wm@AT]^T + u*(Wm@BT)^T)
//   new_m = m @ AT^T + u*BT^T     u = [x|h|m].e  (f32 exact, in prep)
// K0 lmu_pre (512 thr): [wpack 769 | wm2 128 | prep 512] blocks.
//   prep: 32-row tile -> swizzled LDS -> apack [tile][112kk][128r][8]
//   (per-tile contiguous 224KB; 512B-contiguous write segments); u f32.
// K1 lmu_gemm: R13 drain schedule verbatim; A-stage reads tile-major ->
//   each wave-load pulls 1KB CONTIGUOUS (was 64 x 16B @ stride 1792B =
//   4x L2-line amplification).  All else identical to measured-best R13.
// ---------------------------------------------------------------------------

typedef __bf16 bf16;
typedef bf16  bf16x4 __attribute__((ext_vector_type(4)));
typedef bf16  bf16x8 __attribute__((ext_vector_type(8)));
typedef float f32x4  __attribute__((ext_vector_type(4)));
typedef unsigned short u16;

#define BATCH 16384
// ws offsets (u16 units)
#define WPACK 0            // [896/8][512][8] = 458752  (kk>=80 = Wm@AT)
#define ATPACK 458752      // [256/8][256][8] = 65536
#define WUOFF 524288       // 512 f32  (1024 u16)
#define UOFF  525312       // 16384 f32 (32768 u16)
#define APACK 558080       // [128 tile][112 kk][128 r][8] u16
#define TILE_STRIDE 114688 // 112*128*8
// end: 15,238,144 u16 = ~30.5 MB

#define PACKA_BLOCKS 769       // 769*512 = 393728 items
#define WM2_BLOCKS 128
#define PREP_BLOCKS 512        // 32 rows each

__device__ __forceinline__ u16 f2bf(float f) {
  unsigned u = __builtin_bit_cast(unsigned, f);
  u += 0x7FFFu + ((u >> 16) & 1u);   // RNE
  return (u16)(u >> 16);
}

__device__ __forceinline__ void gload16(const u16* g, u16* l) {
  __builtin_amdgcn_global_load_lds(
      (const __attribute__((address_space(1))) unsigned int*)g,
      (__attribute__((address_space(3))) unsigned int*)l, 16, 0, 0);
}

// ---------------- K0: merged prologue (R15-validated, tile-major write) -----
__global__ __launch_bounds__(512) void lmu_pre(
    const float* __restrict__ Wx, const float* __restrict__ Wh,
    const float* __restrict__ Wm, const float* __restrict__ AT,
    const float* __restrict__ BT, const float* __restrict__ x,
    const float* __restrict__ h, const float* __restrict__ m,
    const float* __restrict__ ex, const float* __restrict__ eh,
    const float* __restrict__ em, u16* __restrict__ ws) {
  __shared__ __align__(16) char psm[57344];
  const int bx = blockIdx.x;
  const int t  = threadIdx.x;
  if (bx < PACKA_BLOCKS) {
    int i = bx * 512 + t;
    if (i < 327680) {                     // Wall^T[k][n], k<640
      int j = i & 7, rest = i >> 3;
      int n = rest & 511, kk = rest >> 9;
      int k = kk * 8 + j;
      float v = (k < 128) ? Wx[n * 128 + k] : Wh[n * 512 + (k - 128)];
      ws[WPACK + i] = f2bf(v);
    } else if (i < 393216) {              // atpack[kk][d][j] = AT[d][kk*8+j]
      int tt = i - 327680;
      int j = tt & 7, rest = tt >> 3;
      int d = rest & 255, kk = rest >> 8;
      ws[ATPACK + tt] = f2bf(AT[d * 256 + kk * 8 + j]);
    } else {                              // wu[n] = dot(Wm[n,:], BT)
      int n = i - 393216;
      float s = 0.f;
      for (int k = 0; k < 256; k += 4) {
        float4 wv = *(const float4*)(Wm + (size_t)n * 256 + k);
        float4 bv = *(const float4*)(BT + k);
        s += wv.x * bv.x + wv.y * bv.y + wv.z * bv.z + wv.w * bv.w;
      }
      ((float*)(ws + WUOFF))[n] = s;
    }
  } else if (bx < PACKA_BLOCKS + WM2_BLOCKS) {   // Wm2 = Wm @ AT
    float* wmt = (float*)psm;                    // 16x256 f32
    const int wq = bx - PACKA_BLOCKS;
    const int nb = (wq & 31) * 16, db = (wq >> 5) * 64;
#pragma unroll
    for (int it = 0; it < 2; ++it) {
      int f = it * 512 + t;
      float4 v = *(const float4*)(Wm + (size_t)(nb + (f >> 6)) * 256 + (f & 63) * 4);
      *(float4*)(wmt + (f >> 6) * 256 + (f & 63) * 4) = v;
    }
    __syncthreads();
    const int d = db + (t & 63);
    const int nn = (t >> 6) * 2;
    float acc[2] = {0.f, 0.f};
    for (int k = 0; k < 256; ++k) {
      float atv = AT[(size_t)k * 256 + d];
#pragma unroll
      for (int i2 = 0; i2 < 2; ++i2) acc[i2] += wmt[(nn + i2) * 256 + k] * atv;
    }
    const int kk = 80 + (d >> 3), j = d & 7;
#pragma unroll
    for (int i2 = 0; i2 < 2; ++i2)
      ws[WPACK + ((size_t)kk * 512 + (nb + nn + i2)) * 8 + j] = f2bf(acc[i2]);
  } else {                                       // prep: 32-row tile
    const int px   = bx - PACKA_BLOCKS - WM2_BLOCKS;   // 0..511
    const int lane = t & 63;
    const int wv   = t >> 6;                     // wave 0..7
    float* uo = (float*)(ws + UOFF);
    u16* ap = ws + APACK;
    // phase 1: f32 -> bf16 swizzled LDS rows + u dots (coalesced reads)
#pragma unroll
    for (int rr = 0; rr < 4; ++rr) {
      const int rl = wv * 4 + rr;                // 0..31
      const size_t rg = (size_t)px * 32 + rl;
      float s = 0.f;
#pragma unroll
      for (int j = 0; j < 4; ++j) {
        int slot = j * 64 + lane;
        if (slot < 224) {
          float4 a, e;
          if (slot < 32)       { int c = slot * 4;
            a = *(const float4*)(x + rg * 128 + c); e = *(const float4*)(ex + c); }
          else if (slot < 160) { int c = (slot - 32) * 4;
            a = *(const float4*)(h + rg * 512 + c); e = *(const float4*)(eh + c); }
          else                 { int c = (slot - 160) * 4;
            a = *(const float4*)(m + rg * 256 + c); e = *(const float4*)(em + c); }
          s += a.x * e.x + a.y * e.y + a.z * e.z + a.w * e.w;
          bf16x4 p = {(bf16)a.x, (bf16)a.y, (bf16)a.z, (bf16)a.w};
          int kk = slot >> 1, hf = slot & 1;
          *(bf16x4*)(psm + rl * 1792 + ((kk ^ (rl & 7)) << 4) + hf * 8) = p;
        }
      }
#pragma unroll
      for (int d = 1; d < 64; d <<= 1) s += __shfl_xor(s, d);
      if (lane == 0) uo[rg] = s;
    }
    __syncthreads();
    // phase 2: LDS -> TILE-MAJOR apack (512B-contiguous segments)
    const size_t tbase = (size_t)(px >> 2) * TILE_STRIDE;
    const int rb = (px & 3) * 32;
#pragma unroll
    for (int it = 0; it < 7; ++it) {
      int flat = it * 512 + t;                   // 112kk x 32r
      int kk = flat >> 5, r = flat & 31;
      bf16x8 v = *(const bf16x8*)(psm + r * 1792 + ((kk ^ (r & 7)) << 4));
      *(bf16x8*)(ap + tbase + (size_t)kk * 1024 + (rb + r) * 8) = v;
    }
  }
}

// ---------------- K1: main GEMM (R13 schedule, tile-major A) ----------------
// grid 512 = 128 M-tiles x 4 N-slices; 512 thr; LDS 80KB (2 x 40KB dbuf).
// per 40KB buffer: A [8kb][128r][8] @0, B [8kk][128n][8] @8192 u16,
//                  S [8kk][64n][8] @16384 u16 (staged only for c>=10).
__global__ __launch_bounds__(512, 4) void lmu_gemm(
    const u16* __restrict__ ws, const float* __restrict__ BT,
    float* __restrict__ out) {
  __shared__ __align__(16) u16 smem[2 * 20480];
  const int tid  = threadIdx.x;
  const int lane = tid & 63;
  const int w    = tid >> 6;     // 0..7
  const int wr   = w >> 1;       // 0..3 (32-row slice)
  const int wc   = w & 1;        // 0..1 (64-col slice)
  const int lm   = lane & 15;
  const int kg   = lane >> 4;
  const int bid  = blockIdx.x;
  const int mi   = (bid & 7) | ((bid >> 5) << 3);  // same-M N-slices -> same XCD
  const int nsl  = (bid >> 3) & 3;
  const int b0   = mi * 128;

  const u16* apack = ws + APACK + (size_t)mi * TILE_STRIDE;
  const u16* wpk   = ws + WPACK;
  const u16* atp   = ws + ATPACK;

  f32x4 acc[2][4];    // new_h: 2 Mfrag x 4 Nfrag (32r x 64c per wave)
  f32x4 acc2[2][2];   // new_m: 2 Mfrag x 2 Nfrag (32c per wave)
#pragma unroll
  for (int mt = 0; mt < 2; ++mt) {
#pragma unroll
    for (int ct = 0; ct < 4; ++ct) acc[mt][ct] = (f32x4){0.f, 0.f, 0.f, 0.f};
#pragma unroll
    for (int ct = 0; ct < 2; ++ct) acc2[mt][ct] = (f32x4){0.f, 0.f, 0.f, 0.f};
  }

  auto stage = [&](int c) {
    u16* buf = smem + (c & 1) * 20480;
#pragma unroll
    for (int ph = 0; ph < 2; ++ph) {           // A chunk: 16KB, 1KB/wave contig
      int i = ph * 512 + tid;
      int kb = i >> 7, r = i & 127;
      gload16(apack + (size_t)(c * 8 + kb) * 1024 + r * 8, buf + i * 8);
    }
#pragma unroll
    for (int ph = 0; ph < 2; ++ph) {           // B chunk: 16KB
      int i = ph * 512 + tid;
      int kk = i >> 7, n = i & 127;
      gload16(wpk + ((size_t)(c * 8 + kk) * 512 + nsl * 128 + n) * 8,
              buf + 8192 + i * 8);
    }
    if (c >= 10) {                              // side B (atpack): 8KB
      int kk = tid >> 6, n = tid & 63;
      gload16(atp + ((size_t)((c - 10) * 8 + kk) * 256 + nsl * 64 + n) * 8,
              buf + 16384 + tid * 8);
    }
  };

  auto mma = [&](int c) {
    const u16* buf = smem + (c & 1) * 20480;
#pragma unroll
    for (int ks = 0; ks < 2; ++ks) {
      const int kq = ks * 4 + kg;
      bf16x8 a[2];
#pragma unroll
      for (int mt = 0; mt < 2; ++mt)
        a[mt] = *(const bf16x8*)(buf + (kq * 128 + wr * 32 + mt * 16 + lm) * 8);
#pragma unroll
      for (int ct = 0; ct < 4; ++ct) {
        bf16x8 b = *(const bf16x8*)(buf + 8192 + (kq * 128 + wc * 64 + ct * 16 + lm) * 8);
#pragma unroll
        for (int mt = 0; mt < 2; ++mt)
          acc[mt][ct] = __builtin_amdgcn_mfma_f32_16x16x32_bf16(a[mt], b, acc[mt][ct], 0, 0, 0);
      }
      if (c >= 10) {
#pragma unroll
        for (int ct = 0; ct < 2; ++ct) {
          bf16x8 b = *(const bf16x8*)(buf + 16384 + (kq * 64 + wc * 32 + ct * 16 + lm) * 8);
#pragma unroll
          for (int mt = 0; mt < 2; ++mt)
            acc2[mt][ct] = __builtin_amdgcn_mfma_f32_16x16x32_bf16(a[mt], b, acc2[mt][ct], 0, 0, 0);
        }
      }
    }
  };

  stage(0);
  __syncthreads();
#pragma unroll
  for (int c = 0; c < 14; ++c) {
    if (c < 13) stage(c + 1);   // issue next-chunk loads first (overlap)
    mma(c);                     // compute current from LDS
    __syncthreads();            // drain (measured-best schedule)
  }

  // ---- epilogue ----
  const float* uf  = (const float*)(ws + UOFF);
  const float* wuf = (const float*)(ws + WUOFF);
  float wuv[4], btv[2];
#pragma unroll
  for (int ct = 0; ct < 4; ++ct) wuv[ct] = wuf[nsl * 128 + wc * 64 + ct * 16 + lm];
#pragma unroll
  for (int ct = 0; ct < 2; ++ct) btv[ct] = BT[nsl * 64 + wc * 32 + ct * 16 + lm];
  float* outm = out + (size_t)BATCH * 512;
#pragma unroll
  for (int mt = 0; mt < 2; ++mt)
#pragma unroll
    for (int j = 0; j < 4; ++j) {
      int rl = wr * 32 + mt * 16 + kg * 4 + j;
      size_t row = (size_t)(b0 + rl);
      float uv = uf[row];
#pragma unroll
      for (int ct = 0; ct < 4; ++ct) {
        float v = acc[mt][ct][j] + uv * wuv[ct];
        out[row * 512 + nsl * 128 + wc * 64 + ct * 16 + lm] = 1.0f / (1.0f + __expf(-v));
      }
#pragma unroll
      for (int ct = 0; ct < 2; ++ct)
        outm[row * 256 + nsl * 64 + wc * 32 + ct * 16 + lm] = acc2[mt][ct][j] + uv * btv[ct];
    }
}

extern "C" void kernel_launch(void* const* d_in, const int* in_sizes, int n_in,
                              void* d_out, int out_size, void* d_ws, size_t ws_size,
                              hipStream_t stream) {
  const float* x  = (const float*)d_in[0];
  const float* h  = (const float*)d_in[1];
  const float* m  = (const float*)d_in[2];
  const float* Wx = (const float*)d_in[3];
  const float* Wh = (const float*)d_in[4];
  const float* Wm = (const float*)d_in[5];
  const float* ex = (const float*)d_in[6];
  const float* eh = (const float*)d_in[7];
  const float* em = (const float*)d_in[8];
  const float* AT = (const float*)d_in[9];
  const float* BT = (const float*)d_in[10];
  float* out = (float*)d_out;
  u16* ws = (u16*)d_ws;   // uses ~30.5 MB

  lmu_pre<<<PACKA_BLOCKS + WM2_BLOCKS + PREP_BLOCKS, 512, 0, stream>>>(
      Wx, Wh, Wm, AT, BT, x, h, m, ex, eh, em, ws);
  lmu_gemm<<<512, 512, 0, stream>>>(ws, BT, out);
}